// Round 3
// baseline (101.624 us; speedup 1.0000x reference)
//
#include <hip/hip_runtime.h>

#define B_      2
#define C_      256
#define H_      96
#define W_      96
#define HW_     (H_ * W_)
#define P_      7
#define NROIS_  512
#define SCALE_  0.0625f
#define TSTD_   0.1f

#define NGROUP_ 8                       // channel groups (one per XCD)
#define GC_     (C_ / NGROUP_)          // 32 channels per group

// ---------------------------------------------------------------------------
// Pass 1: CHW -> group-planar [B][g][H*W][32ch].  Group-planar (not plain
// HWC) so each XCD's working set is one CONTIGUOUS 2.36 MB range -> no L2
// set aliasing (interleaved HWC puts group g at offset g*128 mod 1024 ->
// only 1/8 of L2 sets usable).  nt-loads/stores: streamed once, keep L2
// clean for the pool kernel's gathers.
// ---------------------------------------------------------------------------
__global__ __launch_bounds__(256) void nchw_to_gp(const float* __restrict__ in,
                                                  float* __restrict__ out) {
    __shared__ float tile[32][33];          // +1 pad: conflict-free transpose
    const int b  = blockIdx.z;
    const int p0 = blockIdx.x * 32;         // pixel (h*W+w) tile origin
    const int g  = blockIdx.y;              // channel group (32 ch each)
    const int c0 = g * 32;
    const int tx = threadIdx.x;             // 0..31
    const int ty = threadIdx.y;             // 0..7
    const float* src = in  + (size_t)b * (C_ * HW_);
    float*       dst = out + ((size_t)(b * NGROUP_ + g) * HW_) * GC_;
#pragma unroll
    for (int k = 0; k < 32; k += 8)
        tile[ty + k][tx] =
            __builtin_nontemporal_load(&src[(size_t)(c0 + ty + k) * HW_ + p0 + tx]);
    __syncthreads();
#pragma unroll
    for (int k = 0; k < 32; k += 8)
        __builtin_nontemporal_store(tile[tx][ty + k],
                                    &dst[(size_t)(p0 + ty + k) * GC_ + tx]);
}

// ---------------------------------------------------------------------------
// Pass 2: block = (roi n, group g), g = blockIdx.x & 7 -> round-robin XCD
// dispatch pins group g's contiguous 2.36 MB slice in that XCD's L2.
// 8 lanes/bin x float4 = 32 ch = one 128 B line per corner.  Branchless
// validity (divergent per-lane bins) so all 16 gathers issue back-to-back.
// Output staged in LDS (global layout), written coalesced + nontemporal.
// ---------------------------------------------------------------------------
__global__ __launch_bounds__(256) void dpsroi_pool3(const float* __restrict__ feat,  // group-planar
                                                    const float* __restrict__ rois,
                                                    const float* __restrict__ trans,
                                                    float* __restrict__ out) {
    __shared__ float sout[GC_ * P_ * P_];   // 32*49*4 = 6272 B, global layout

    const int blk = blockIdx.x;
    const int g   = blk & (NGROUP_ - 1);
    const int n   = blk >> 3;
    const int tid = threadIdx.x;
    const int cl  = (tid & 7) * 4;          // channel-in-group: 0,4,...,28

    // ROI geometry (block-uniform)
    const int   broi = (int)rois[n * 5 + 0];
    const float x1 = rintf(rois[n * 5 + 1]) * SCALE_ - 0.5f;
    const float y1 = rintf(rois[n * 5 + 2]) * SCALE_ - 0.5f;
    const float x2 = (rintf(rois[n * 5 + 3]) + 1.0f) * SCALE_ - 0.5f;
    const float y2 = (rintf(rois[n * 5 + 4]) + 1.0f) * SCALE_ - 0.5f;
    const float rw = fmaxf(x2 - x1, 0.1f);
    const float rh = fmaxf(y2 - y1, 0.1f);
    const float bin_w = rw * (1.0f / 7.0f);
    const float bin_h = rh * (1.0f / 7.0f);
    const float sub_w = bin_w * 0.5f;
    const float sub_h = bin_h * 0.5f;

    const float* fb = feat + ((size_t)(broi * NGROUP_ + g) * HW_) * GC_ + cl;

    // 256 threads = 8 lanes/bin x 32 bin-slots; 49 bins -> 2 sweeps.
    for (int bin = tid >> 3; bin < P_ * P_; bin += 32) {
        const int pi = bin / P_;
        const int pj = bin - pi * P_;

        const float tx = trans[((n * 2 + 0) * P_ + pi) * P_ + pj] * TSTD_;
        const float ty = trans[((n * 2 + 1) * P_ + pi) * P_ + pj] * TSTD_;
        const float wstart = (float)pj * bin_w + x1 + tx * rw;
        const float hstart = (float)pi * bin_h + y1 + ty * rh;

        // --- branchless: compute 4 samples' corners/weights, then 16 loads ---
        float w4[4], h4[4];
#pragma unroll
        for (int s = 0; s < 4; ++s) {
            w4[s] = wstart + (float)(s & 1) * sub_w;
            h4[s] = hstart + (float)(s >> 1) * sub_h;
        }
        int   cnt = 0;
        float wt[4][4];                     // [sample][corner]
        int   ofs[4][4];                    // pixel offsets
#pragma unroll
        for (int s = 0; s < 4; ++s) {
            const float w = w4[s], h = h4[s];
            const bool valid = (w >= -0.5f) & (w <= (float)W_ - 0.5f) &
                               (h >= -0.5f) & (h <= (float)H_ - 0.5f);
            cnt += valid ? 1 : 0;
            const float vf = valid ? 1.0f : 0.0f;
            const float wc  = fminf(fmaxf(w, 0.0f), (float)(W_ - 1));
            const float hc  = fminf(fmaxf(h, 0.0f), (float)(H_ - 1));
            const float x0f = floorf(wc), y0f = floorf(hc);
            const float dx  = wc - x0f,   dy  = hc - y0f;
            const int   x0  = (int)x0f,   y0  = (int)y0f;
            const int   xp  = (int)ceilf(wc), yp = (int)ceilf(hc);
            wt[s][0] = vf * (1.0f - dx) * (1.0f - dy);
            wt[s][1] = vf * dx * (1.0f - dy);
            wt[s][2] = vf * (1.0f - dx) * dy;
            wt[s][3] = vf * dx * dy;
            ofs[s][0] = y0 * W_ + x0;
            ofs[s][1] = y0 * W_ + xp;
            ofs[s][2] = yp * W_ + x0;
            ofs[s][3] = yp * W_ + xp;
        }

        float acc0 = 0.f, acc1 = 0.f, acc2 = 0.f, acc3 = 0.f;
#pragma unroll
        for (int s = 0; s < 4; ++s) {
            float4 v[4];
#pragma unroll
            for (int c = 0; c < 4; ++c)
                v[c] = *(const float4*)(fb + (size_t)ofs[s][c] * GC_);
#pragma unroll
            for (int c = 0; c < 4; ++c) {
                acc0 += wt[s][c] * v[c].x;
                acc1 += wt[s][c] * v[c].y;
                acc2 += wt[s][c] * v[c].z;
                acc3 += wt[s][c] * v[c].w;
            }
        }

        const float inv = (cnt > 0) ? (1.0f / (float)cnt) : 0.0f;
        sout[(cl + 0) * (P_ * P_) + bin] = acc0 * inv;
        sout[(cl + 1) * (P_ * P_) + bin] = acc1 * inv;
        sout[(cl + 2) * (P_ * P_) + bin] = acc2 * inv;
        sout[(cl + 3) * (P_ * P_) + bin] = acc3 * inv;
    }

    __syncthreads();
    // out[n, g*32 : (g+1)*32, :, :] is contiguous: 32*49 floats
    float* outn = out + ((size_t)n * C_ + g * GC_) * (P_ * P_);
    for (int f = tid; f < GC_ * P_ * P_; f += 256)
        __builtin_nontemporal_store(sout[f], &outn[f]);
}

extern "C" void kernel_launch(void* const* d_in, const int* in_sizes, int n_in,
                              void* d_out, int out_size, void* d_ws, size_t ws_size,
                              hipStream_t stream) {
    const float* feat  = (const float*)d_in[0];   // (2,256,96,96)
    const float* rois  = (const float*)d_in[1];   // (512,5)
    const float* trans = (const float*)d_in[2];   // (512,2,7,7)
    float* out = (float*)d_out;                   // (512,256,7,7)

    float* gp = (float*)d_ws;                     // 18.9 MB; ws is 256 MiB
    dim3 tb(32, 8);
    dim3 tg(HW_ / 32, NGROUP_, B_);
    nchw_to_gp<<<tg, tb, 0, stream>>>(feat, gp);
    dpsroi_pool3<<<NROIS_ * NGROUP_, 256, 0, stream>>>(gp, rois, trans, out);
}

// Round 4
// 92.545 us; speedup vs baseline: 1.0981x; 1.0981x over previous
//
#include <hip/hip_runtime.h>

#define B_      2
#define C_      256
#define H_      96
#define W_      96
#define HW_     (H_ * W_)
#define P_      7
#define PP_     (P_ * P_)
#define NROIS_  512
#define SCALE_  0.0625f
#define TSTD_   0.1f

#define NGROUP_ 8                       // channel groups (one per XCD)
#define GC_     (C_ / NGROUP_)          // 32 channels per group

// f32 -> bf16 (round-to-nearest-even), as raw ushort bits
__device__ __forceinline__ unsigned f2bf(float f) {
    union { float f; unsigned u; } x; x.f = f;
    return (x.u + 0x7fffu + ((x.u >> 16) & 1u)) >> 16;
}
// unpack bf16 pair from a dword
__device__ __forceinline__ float bf_lo(unsigned u) {
    union { unsigned i; float f; } x; x.i = u << 16; return x.f;
}
__device__ __forceinline__ float bf_hi(unsigned u) {
    union { unsigned i; float f; } x; x.i = u & 0xffff0000u; return x.f;
}

// ---------------------------------------------------------------------------
// Pass 1: f32 CHW -> bf16 group-planar [b][g][HW][32ch].
//  * bf16 halves the pool kernel's gather bytes (threshold is bf16-sized).
//  * 32ch x 2B = 64 B per pixel -> ONE cache line per bilinear corner.
//  * g = blockIdx.x & 7 matches the pool kernel's g mapping, so under
//    round-robin block->XCD dispatch the producer and consumer of group g
//    share an XCD (stores land L2-warm).  Plain stores (NOT nontemporal --
//    R3 showed nt-stores on this tensor evict the pool's input).
// ---------------------------------------------------------------------------
__global__ __launch_bounds__(256) void nchw_to_gp_bf16(const float* __restrict__ in,
                                                       ushort* __restrict__ out) {
    __shared__ float tile[32][33];          // [ch][px], +1 pad
    const int b   = blockIdx.z;
    const int g   = blockIdx.x & (NGROUP_ - 1);
    const int p0  = (blockIdx.x >> 3) * 32; // pixel tile origin
    const int c0  = g * 32;                 // channel tile origin
    const int tid = threadIdx.x;

    const float* src = in + (size_t)b * (C_ * HW_);
    ushort*      dst = out + ((size_t)(b * NGROUP_ + g) * HW_) * GC_;

    // read: 32 px (lanes) x 8 ch per pass, 4 passes, coalesced on pixels
    const int px = tid & 31, cr = tid >> 5;
#pragma unroll
    for (int k = 0; k < 32; k += 8)
        tile[cr + k][px] =
            __builtin_nontemporal_load(&src[(size_t)(c0 + cr + k) * HW_ + p0 + px]);
    __syncthreads();

    // write: pack ch pairs into dwords; 16 pairs x 16 px per pass, 2 passes
    const int cp = tid & 15, py = tid >> 4;  // cp: ch-pair, py: pixel
    unsigned* dst32 = (unsigned*)dst;
#pragma unroll
    for (int k = 0; k < 32; k += 16) {
        const int p = py + k;
        const unsigned u0 = f2bf(tile[2 * cp + 0][p]);
        const unsigned u1 = f2bf(tile[2 * cp + 1][p]);
        dst32[(size_t)(p0 + p) * (GC_ / 2) + cp] = u0 | (u1 << 16);
    }
}

// ---------------------------------------------------------------------------
// Pass 2: block = (roi n, group g), g = blockIdx.x & 7 (XCD affinity).
// 4 lanes/bin x uint4 (8 bf16 ch) = 64 B = one line per corner.
// bin = tid>>2 in [0,64): single sweep, all 16 gathers issue back-to-back.
// Output staged in LDS (global layout), written coalesced + nontemporal.
// ---------------------------------------------------------------------------
__global__ __launch_bounds__(256) void dpsroi_pool4(const ushort* __restrict__ feat, // bf16 gp
                                                    const float* __restrict__ rois,
                                                    const float* __restrict__ trans,
                                                    float* __restrict__ out) {
    __shared__ float sout[GC_ * PP_];       // 32*49*4 = 6272 B, global layout

    const int blk = blockIdx.x;
    const int g   = blk & (NGROUP_ - 1);
    const int n   = blk >> 3;
    const int tid = threadIdx.x;
    const int bin = tid >> 2;               // 0..63 (49 active)
    const int ch0 = (tid & 3) * 8;          // 8 channels per lane

    // ROI geometry (block-uniform)
    const int   broi = (int)rois[n * 5 + 0];
    const float x1 = rintf(rois[n * 5 + 1]) * SCALE_ - 0.5f;
    const float y1 = rintf(rois[n * 5 + 2]) * SCALE_ - 0.5f;
    const float x2 = (rintf(rois[n * 5 + 3]) + 1.0f) * SCALE_ - 0.5f;
    const float y2 = (rintf(rois[n * 5 + 4]) + 1.0f) * SCALE_ - 0.5f;
    const float rw = fmaxf(x2 - x1, 0.1f);
    const float rh = fmaxf(y2 - y1, 0.1f);
    const float bin_w = rw * (1.0f / 7.0f);
    const float bin_h = rh * (1.0f / 7.0f);
    const float sub_w = bin_w * 0.5f;
    const float sub_h = bin_h * 0.5f;

    const ushort* fb = feat + ((size_t)(broi * NGROUP_ + g) * HW_) * GC_ + ch0;

    float acc[8] = {0.f, 0.f, 0.f, 0.f, 0.f, 0.f, 0.f, 0.f};
    int cnt = 0;

    if (bin < PP_) {
        const int pi = bin / P_;
        const int pj = bin - pi * P_;
        const float tx = trans[((n * 2 + 0) * P_ + pi) * P_ + pj] * TSTD_;
        const float ty = trans[((n * 2 + 1) * P_ + pi) * P_ + pj] * TSTD_;
        const float wstart = (float)pj * bin_w + x1 + tx * rw;
        const float hstart = (float)pi * bin_h + y1 + ty * rh;

        float wt[4][4];
        int   ofs[4][4];
#pragma unroll
        for (int s = 0; s < 4; ++s) {
            const float w = wstart + (float)(s & 1) * sub_w;
            const float h = hstart + (float)(s >> 1) * sub_h;
            const bool valid = (w >= -0.5f) & (w <= (float)W_ - 0.5f) &
                               (h >= -0.5f) & (h <= (float)H_ - 0.5f);
            cnt += valid ? 1 : 0;
            const float vf = valid ? 1.0f : 0.0f;
            const float wc  = fminf(fmaxf(w, 0.0f), (float)(W_ - 1));
            const float hc  = fminf(fmaxf(h, 0.0f), (float)(H_ - 1));
            const float x0f = floorf(wc), y0f = floorf(hc);
            const float dx  = wc - x0f,   dy  = hc - y0f;
            const int   x0  = (int)x0f,   y0  = (int)y0f;
            const int   xp  = (int)ceilf(wc), yp = (int)ceilf(hc);
            wt[s][0] = vf * (1.0f - dx) * (1.0f - dy);
            wt[s][1] = vf * dx * (1.0f - dy);
            wt[s][2] = vf * (1.0f - dx) * dy;
            wt[s][3] = vf * dx * dy;
            ofs[s][0] = y0 * W_ + x0;
            ofs[s][1] = y0 * W_ + xp;
            ofs[s][2] = yp * W_ + x0;
            ofs[s][3] = yp * W_ + xp;
        }

#pragma unroll
        for (int s = 0; s < 4; ++s) {
            uint4 v[4];
#pragma unroll
            for (int c = 0; c < 4; ++c)
                v[c] = *(const uint4*)(fb + (size_t)ofs[s][c] * GC_);
#pragma unroll
            for (int c = 0; c < 4; ++c) {
                const float wgt = wt[s][c];
                acc[0] += wgt * bf_lo(v[c].x);
                acc[1] += wgt * bf_hi(v[c].x);
                acc[2] += wgt * bf_lo(v[c].y);
                acc[3] += wgt * bf_hi(v[c].y);
                acc[4] += wgt * bf_lo(v[c].z);
                acc[5] += wgt * bf_hi(v[c].z);
                acc[6] += wgt * bf_lo(v[c].w);
                acc[7] += wgt * bf_hi(v[c].w);
            }
        }

        const float inv = (cnt > 0) ? (1.0f / (float)cnt) : 0.0f;
#pragma unroll
        for (int j = 0; j < 8; ++j)
            sout[(ch0 + j) * PP_ + bin] = acc[j] * inv;
    }

    __syncthreads();
    // out[n, g*32 : (g+1)*32, :, :] contiguous: 32*49 = 1568 floats
    float* outn = out + ((size_t)n * C_ + g * GC_) * PP_;
    for (int f = tid; f < GC_ * PP_; f += 256)
        __builtin_nontemporal_store(sout[f], &outn[f]);
}

extern "C" void kernel_launch(void* const* d_in, const int* in_sizes, int n_in,
                              void* d_out, int out_size, void* d_ws, size_t ws_size,
                              hipStream_t stream) {
    const float* feat  = (const float*)d_in[0];   // (2,256,96,96) f32
    const float* rois  = (const float*)d_in[1];   // (512,5)
    const float* trans = (const float*)d_in[2];   // (512,2,7,7)
    float* out = (float*)d_out;                   // (512,256,7,7) f32

    ushort* gp = (ushort*)d_ws;                   // bf16 group-planar, 9.4 MB
    dim3 tb(256);
    dim3 tg((HW_ / 32) * NGROUP_, 1, B_);         // g = blockIdx.x & 7
    nchw_to_gp_bf16<<<tg, tb, 0, stream>>>(feat, gp);
    dpsroi_pool4<<<NROIS_ * NGROUP_, 256, 0, stream>>>(gp, rois, trans, out);
}